// Round 10
// baseline (1507.284 us; speedup 1.0000x reference)
//
#include <hip/hip_runtime.h>
#include <stdint.h>

#define HH 1024
#define WW 1536
#define NN (HH * WW)

// ---- dilation tiling ----
#define SS 10                 // steps per launch (halo width)
#define BX 96                 // core tile X (W/BX = 16)
#define BY 64                 // core tile Y (H/BY = 16)
#define TX (BX + 2 * SS)      // 116 (halo'd tile X)
#define TY (BY + 2 * SS)      // 84  (halo'd tile Y)
#define LSTRIDE 124           // LDS row stride (ints), mult of 4, >= 4+TX+1
#define LROWS (TY + 2)        // 86 (zero ring top/bottom)
#define NGRP (TY * (TX / 4))  // 2436 int4-groups per tile
#define NPT4 5                // ceil(NGRP / 512)

static __device__ __forceinline__ int imax(int a, int b) { return a > b ? a : b; }

// ---- kernel 1: dst ids (exact IEEE, no contraction) + fore scatter into y1 ----
__global__ void k_prep(const float* __restrict__ y_hat,
                       const float* __restrict__ df,
                       int* __restrict__ dst_ids,
                       int* __restrict__ y1)
{
    int i = blockIdx.x * blockDim.x + threadIdx.x;
    if (i >= NN) return;
    int r = i / WW, c = i % WW;
    float a = df[i];          // df_hat[0,:,:]
    float b = df[NN + i];     // df_hat[1,:,:]
    float ss  = __fadd_rn(__fmul_rn(a, a), __fmul_rn(b, b));
    float len = __fsqrt_rn(ss);
    float x   = __fadd_rn(len, 1e-19f);
    float ur  = __fdiv_rn(a, x);
    float uc  = __fdiv_rn(b, x);
    float dfc = fminf(fmaxf(len, 3.0f), 6.0f);
    float dr  = __fadd_rn((float)r, __fmul_rn(ur, dfc));
    float dc  = __fadd_rn((float)c, __fmul_rn(uc, dfc));
    dr = fminf(fmaxf(dr, 0.0f), (float)(HH - 1));
    dc = fminf(fmaxf(dc, 0.0f), (float)(WW - 1));
    int ir = (int)rintf(dr);   // round half-to-even, matches jnp/np.round
    int ic = (int)rintf(dc);
    int d = ir * WW + ic;
    dst_ids[i] = d;
    if (y_hat[i] > 0.5f) atomicAdd(&y1[d], 1);
}

// ---- kernel 2: second scatter (y2[dst[i]] += y1[i]) ----
__global__ void k_scatter2(const int* __restrict__ y1,
                           const int* __restrict__ dst,
                           int* __restrict__ y2)
{
    int i = blockIdx.x * blockDim.x + threadIdx.x;
    if (i >= NN) return;
    int v = y1[i];
    if (v) atomicAdd(&y2[dst[i]], v);
}

// ---- kernel 3: horizontal 5-sum of y2 ----
__global__ void k_hsum(const int* __restrict__ y2, int* __restrict__ hs)
{
    int i = blockIdx.x * blockDim.x + threadIdx.x;
    if (i >= NN) return;
    int c = i % WW;
    int s = 0;
#pragma unroll
    for (int d = -2; d <= 2; ++d) {
        int cc = c + d;
        if (cc >= 0 && cc < WW) s += y2[i + d];
    }
    hs[i] = s;
}

// ---- kernel 4: vertical 5-sum + avgpool>=0.5 threshold (exact integer test) ----
__global__ void k_vthr(const int* __restrict__ hs, int* __restrict__ m0)
{
    int i = blockIdx.x * blockDim.x + threadIdx.x;
    if (i >= NN) return;
    int r = i / WW, c = i % WW;
    int s = 0;
#pragma unroll
    for (int d = -2; d <= 2; ++d) {
        int rr = r + d;
        if (rr >= 0 && rr < HH) s += hs[i + d * WW];
    }
    int rows = min(r + 2, HH - 1) - max(r - 2, 0) + 1;
    int cols = min(c + 2, WW - 1) - max(c - 2, 0) + 1;
    m0[i] = (2 * s >= rows * cols) ? 1 : 0;  // s/c >= 0.5 exactly
}

// ---- kernel 5: 3x3-cross erosion (border = foreground) + label init ----
__global__ void k_erode(const int* __restrict__ m0, int* __restrict__ lab)
{
    int i = blockIdx.x * blockDim.x + threadIdx.x;
    if (i >= NN) return;
    int r = i / WW, c = i % WW;
    int m = m0[i];
    if (m) {
        if (r > 0)      m &= m0[i - WW];
        if (r < HH - 1) m &= m0[i + WW];
        if (c > 0)      m &= m0[i - 1];
        if (c < WW - 1) m &= m0[i + 1];
    }
    lab[i] = m ? (i + 1) : 0;
}

// ---- kernel 6: 10 masked 3x3 max-dilation steps in LDS (halo'd tile) ----
__global__ __launch_bounds__(512) void k_dilate(const int* __restrict__ in,
                                                int* __restrict__ out)
{
    __shared__ int L[LROWS * LSTRIDE];
    const int tx = threadIdx.x;
    const int r0 = blockIdx.y * BY - SS;
    const int c0 = blockIdx.x * BX - SS;

    // zero (ring must be 0 = outside-image / reduce_window pad value)
    for (int p = tx; p < LROWS * LSTRIDE; p += 512) L[p] = 0;
    __syncthreads();
    // load halo'd tile
    for (int p = tx; p < TY * TX; p += 512) {
        int tr = p / TX, tc = p % TX;
        int gr = r0 + tr, gc = c0 + tc;
        int v = 0;
        if (gr >= 0 && gr < HH && gc >= 0 && gc < WW) v = in[gr * WW + gc];
        L[(tr + 1) * LSTRIDE + 4 + tc] = v;
    }
    __syncthreads();

    for (int s = 0; s < SS; ++s) {
        int4 nv[NPT4];
#pragma unroll
        for (int k = 0; k < NPT4; ++k) {
            int g = tx + k * 512;
            int4 res = make_int4(0, 0, 0, 0);
            if (g < NGRP) {
                int gr  = g / (TX / 4);
                int gc  = (g - gr * (TX / 4)) * 4;
                int idx = (gr + 1) * LSTRIDE + 4 + gc;  // 16B-aligned
                int4 mid = *(const int4*)&L[idx];
                int4 up  = *(const int4*)&L[idx - LSTRIDE];
                int4 dn  = *(const int4*)&L[idx + LSTRIDE];
                int ul = L[idx - LSTRIDE - 1], ml = L[idx - 1], dl = L[idx + LSTRIDE - 1];
                int uR = L[idx - LSTRIDE + 4], mR = L[idx + 4], dR = L[idx + LSTRIDE + 4];
                int vl = imax(imax(ul, ml), dl);
                int v0 = imax(imax(up.x, mid.x), dn.x);
                int v1 = imax(imax(up.y, mid.y), dn.y);
                int v2 = imax(imax(up.z, mid.z), dn.z);
                int v3 = imax(imax(up.w, mid.w), dn.w);
                int vr = imax(imax(uR, mR), dR);
                res.x = (mid.x > 0) ? imax(imax(vl, v0), v1) : 0;
                res.y = (mid.y > 0) ? imax(imax(v0, v1), v2) : 0;
                res.z = (mid.z > 0) ? imax(imax(v1, v2), v3) : 0;
                res.w = (mid.w > 0) ? imax(imax(v2, v3), vr) : 0;
            }
            nv[k] = res;
        }
        __syncthreads();
#pragma unroll
        for (int k = 0; k < NPT4; ++k) {
            int g = tx + k * 512;
            if (g < NGRP) {
                int gr = g / (TX / 4);
                int gc = (g - gr * (TX / 4)) * 4;
                *(int4*)&L[(gr + 1) * LSTRIDE + 4 + gc] = nv[k];
            }
        }
        __syncthreads();
    }

    // store exact core
    for (int q = tx; q < BX * BY; q += 512) {
        int cr = q / BX, cc = q % BX;
        out[(blockIdx.y * BY + cr) * WW + blockIdx.x * BX + cc] =
            L[(SS + cr + 1) * LSTRIDE + 4 + SS + cc];
    }
}

// ---- kernel 7: 8-deep gather chain + fore mask + size histogram ----
__global__ void k_hist(const float* __restrict__ y_hat,
                       const int* __restrict__ dst,
                       const int* __restrict__ lab,
                       int* __restrict__ Li_out,
                       int* __restrict__ count)
{
    int i = blockIdx.x * blockDim.x + threadIdx.x;
    if (i >= NN) return;
    int j = i;
#pragma unroll
    for (int t = 0; t < 8; ++t) j = dst[j];
    int L = lab[j];
    if (!(y_hat[i] > 0.5f)) L = 0;
    Li_out[i] = L;
    if (L > 0) atomicAdd(&count[L], 1);
}

// ---- kernel 8: size-threshold broadcast (in-place int -> float in d_out) ----
__global__ void k_final(const int* __restrict__ Li,
                        const int* __restrict__ count,
                        float* __restrict__ out)
{
    int i = blockIdx.x * blockDim.x + threadIdx.x;
    if (i >= NN) return;
    int L = Li[i];
    float v = (L > 0 && count[L] > 256) ? (float)L : 0.0f;
    out[i] = v;
}

extern "C" void kernel_launch(void* const* d_in, const int* in_sizes, int n_in,
                              void* d_out, int out_size, void* d_ws, size_t ws_size,
                              hipStream_t stream)
{
    const float* y_hat = (const float*)d_in[0];
    const float* df    = (const float*)d_in[1];

    int* W0 = (int*)d_ws;        // dst_ids                (N)
    int* W1 = W0 + NN;           // y1 / mask0 / lab ping  (N)
    int* W2 = W1 + NN;           // y2 / count             (N+1, padded)
    int* W3 = W2 + (NN + 64);    // hs / lab pong (final)  (N)
    float* out = (float*)d_out;

    hipMemsetAsync(W1, 0, (size_t)NN * sizeof(int), stream);           // y1 = 0
    hipMemsetAsync(W2, 0, (size_t)(NN + 1) * sizeof(int), stream);     // y2 = 0

    dim3 blk(256), grd((NN + 255) / 256);
    k_prep<<<grd, blk, 0, stream>>>(y_hat, df, W0, W1);
    k_scatter2<<<grd, blk, 0, stream>>>(W1, W0, W2);
    k_hsum<<<grd, blk, 0, stream>>>(W2, W3);
    k_vthr<<<grd, blk, 0, stream>>>(W3, W1);
    k_erode<<<grd, blk, 0, stream>>>(W1, W3);

    // 300 dilation steps = 30 launches x 10 in-LDS steps, ping-pong W3<->W1
    dim3 gd(WW / BX, HH / BY);   // (16,16)
    int* pa = W3;
    int* pb = W1;
    for (int t = 0; t < 30; ++t) {
        k_dilate<<<gd, 512, 0, stream>>>(pa, pb);
        int* tmp = pa; pa = pb; pb = tmp;
    }
    // 30 swaps (even) -> final labels in W3 (== pa)

    hipMemsetAsync(W2, 0, (size_t)(NN + 1) * sizeof(int), stream);     // count = 0
    k_hist<<<grd, blk, 0, stream>>>(y_hat, W0, pa, (int*)d_out, W2);
    k_final<<<grd, blk, 0, stream>>>((const int*)d_out, W2, out);
}

// Round 15
// 931.106 us; speedup vs baseline: 1.6188x; 1.6188x over previous
//
#include <hip/hip_runtime.h>
#include <stdint.h>

#define HH 1024
#define WW 1536
#define NN (HH * WW)

// ---- dilation tiling ----
#define SS 10                 // steps per launch (halo width)
#define BX 96                 // core tile X (W/BX = 16)
#define BY 64                 // core tile Y (H/BY = 16)
#define TX (BX + 2 * SS)      // 116 (halo'd tile X)
#define TY (BY + 2 * SS)      // 84  (halo'd tile Y)
#define LSTRIDE 128           // LDS row stride (ints) = 32 int4 groups exactly
#define LROWS (TY + 2)        // 86 (zero ring top/bottom)
#define NSET (TY / 2)         // 42 wave-sets: each wave covers 2 rows x 32 groups

static __device__ __forceinline__ int imax(int a, int b) { return a > b ? a : b; }

// ---- kernel 1: dst ids (exact IEEE, no contraction) + fore scatter into y1 ----
__global__ void k_prep(const float* __restrict__ y_hat,
                       const float* __restrict__ df,
                       int* __restrict__ dst_ids,
                       int* __restrict__ y1)
{
    int i = blockIdx.x * blockDim.x + threadIdx.x;
    if (i >= NN) return;
    int r = i / WW, c = i % WW;
    float a = df[i];          // df_hat[0,:,:]
    float b = df[NN + i];     // df_hat[1,:,:]
    float ss  = __fadd_rn(__fmul_rn(a, a), __fmul_rn(b, b));
    float len = __fsqrt_rn(ss);
    float x   = __fadd_rn(len, 1e-19f);
    float ur  = __fdiv_rn(a, x);
    float uc  = __fdiv_rn(b, x);
    float dfc = fminf(fmaxf(len, 3.0f), 6.0f);
    float dr  = __fadd_rn((float)r, __fmul_rn(ur, dfc));
    float dc  = __fadd_rn((float)c, __fmul_rn(uc, dfc));
    dr = fminf(fmaxf(dr, 0.0f), (float)(HH - 1));
    dc = fminf(fmaxf(dc, 0.0f), (float)(WW - 1));
    int ir = (int)rintf(dr);   // round half-to-even, matches jnp/np.round
    int ic = (int)rintf(dc);
    int d = ir * WW + ic;
    dst_ids[i] = d;
    if (y_hat[i] > 0.5f) atomicAdd(&y1[d], 1);
}

// ---- kernel 2: second scatter (y2[dst[i]] += y1[i]) ----
__global__ void k_scatter2(const int* __restrict__ y1,
                           const int* __restrict__ dst,
                           int* __restrict__ y2)
{
    int i = blockIdx.x * blockDim.x + threadIdx.x;
    if (i >= NN) return;
    int v = y1[i];
    if (v) atomicAdd(&y2[dst[i]], v);
}

// ---- kernel 3: horizontal 5-sum of y2 ----
__global__ void k_hsum(const int* __restrict__ y2, int* __restrict__ hs)
{
    int i = blockIdx.x * blockDim.x + threadIdx.x;
    if (i >= NN) return;
    int c = i % WW;
    int s = 0;
#pragma unroll
    for (int d = -2; d <= 2; ++d) {
        int cc = c + d;
        if (cc >= 0 && cc < WW) s += y2[i + d];
    }
    hs[i] = s;
}

// ---- kernel 4: vertical 5-sum + avgpool>=0.5 threshold (exact integer test) ----
__global__ void k_vthr(const int* __restrict__ hs, int* __restrict__ m0)
{
    int i = blockIdx.x * blockDim.x + threadIdx.x;
    if (i >= NN) return;
    int r = i / WW, c = i % WW;
    int s = 0;
#pragma unroll
    for (int d = -2; d <= 2; ++d) {
        int rr = r + d;
        if (rr >= 0 && rr < HH) s += hs[i + d * WW];
    }
    int rows = min(r + 2, HH - 1) - max(r - 2, 0) + 1;
    int cols = min(c + 2, WW - 1) - max(c - 2, 0) + 1;
    m0[i] = (2 * s >= rows * cols) ? 1 : 0;  // s/c >= 0.5 exactly
}

// ---- kernel 5: 3x3-cross erosion (border = foreground) + label init ----
__global__ void k_erode(const int* __restrict__ m0, int* __restrict__ lab)
{
    int i = blockIdx.x * blockDim.x + threadIdx.x;
    if (i >= NN) return;
    int r = i / WW, c = i % WW;
    int m = m0[i];
    if (m) {
        if (r > 0)      m &= m0[i - WW];
        if (r < HH - 1) m &= m0[i + WW];
        if (c > 0)      m &= m0[i - 1];
        if (c < WW - 1) m &= m0[i + 1];
    }
    lab[i] = m ? (i + 1) : 0;
}

// ---- kernel 6: 10 masked 3x3 max-dilation steps in LDS ----
// Wave-aligned layout: LSTRIDE=128 ints = 32 int4-groups per row; each wave
// owns 2 rows (lane>>5) x 32 groups (lane&31). All ds_read/ds_write are the
// perfect consecutive b128 pattern (conflict-free); left/right neighbor ints
// come from width-32 lane shuffles (crossbar, conflict-free) instead of the
// 8-way-conflicted stride-16B b32 reads of the previous version.
// Groups 0, 30, 31 of each row are pad (tile ints live at [4,120)); their
// mid==0 masks the result to 0, so shuffle edge lanes are harmless and pads
// stay zero inductively.
__global__ __launch_bounds__(512) void k_dilate(const int* __restrict__ in,
                                                int* __restrict__ out)
{
    __shared__ int L[LROWS * LSTRIDE];
    const int tx   = threadIdx.x;
    const int wid  = tx >> 6;
    const int lane = tx & 63;
    const int half = lane >> 5;     // which of the wave's 2 rows
    const int g    = lane & 31;     // int4-group within row
    const int r0 = blockIdx.y * BY - SS;
    const int c0 = blockIdx.x * BX - SS;

    // zero everything (ring rows, pad cols = reduce_window pad value 0)
    for (int p = tx; p < LROWS * LSTRIDE; p += 512) L[p] = 0;
    __syncthreads();
    // load halo'd tile
    for (int p = tx; p < TY * TX; p += 512) {
        int tr = p / TX, tc = p - tr * TX;
        int gr = r0 + tr, gc = c0 + tc;
        int v = 0;
        if (gr >= 0 && gr < HH && gc >= 0 && gc < WW) v = in[gr * WW + gc];
        L[(tr + 1) * LSTRIDE + 4 + tc] = v;
    }
    __syncthreads();

    for (int s = 0; s < SS; ++s) {
        int4 nv[6];
#pragma unroll
        for (int k = 0; k < 6; ++k) {
            int S = wid + 8 * k;            // wave-uniform set index
            int4 res = make_int4(0, 0, 0, 0);
            if (S < NSET) {                 // wave-uniform branch
                int rr  = 1 + 2 * S + half; // rows 1..84
                int idx = rr * LSTRIDE + 4 * g;
                int4 mid = *(const int4*)&L[idx];
                int4 up  = *(const int4*)&L[idx - LSTRIDE];
                int4 dn  = *(const int4*)&L[idx + LSTRIDE];
                int ul = __shfl_up(up.w, 1, 32);
                int ml = __shfl_up(mid.w, 1, 32);
                int dl = __shfl_up(dn.w, 1, 32);
                int uR = __shfl_down(up.x, 1, 32);
                int mR = __shfl_down(mid.x, 1, 32);
                int dR = __shfl_down(dn.x, 1, 32);
                int vl = imax(imax(ul, ml), dl);
                int v0 = imax(imax(up.x, mid.x), dn.x);
                int v1 = imax(imax(up.y, mid.y), dn.y);
                int v2 = imax(imax(up.z, mid.z), dn.z);
                int v3 = imax(imax(up.w, mid.w), dn.w);
                int vr = imax(imax(uR, mR), dR);
                res.x = (mid.x > 0) ? imax(imax(vl, v0), v1) : 0;
                res.y = (mid.y > 0) ? imax(imax(v0, v1), v2) : 0;
                res.z = (mid.z > 0) ? imax(imax(v1, v2), v3) : 0;
                res.w = (mid.w > 0) ? imax(imax(v2, v3), vr) : 0;
            }
            nv[k] = res;
        }
        __syncthreads();
#pragma unroll
        for (int k = 0; k < 6; ++k) {
            int S = wid + 8 * k;
            if (S < NSET) {
                int rr  = 1 + 2 * S + half;
                int idx = rr * LSTRIDE + 4 * g;
                *(int4*)&L[idx] = nv[k];
            }
        }
        __syncthreads();
    }

    // store exact core
    for (int q = tx; q < BX * BY; q += 512) {
        int cr = q / BX, cc = q - cr * BX;
        out[(blockIdx.y * BY + cr) * WW + blockIdx.x * BX + cc] =
            L[(SS + cr + 1) * LSTRIDE + 4 + SS + cc];
    }
}

// ---- kernel 7: 8-deep gather chain + fore mask + size histogram ----
__global__ void k_hist(const float* __restrict__ y_hat,
                       const int* __restrict__ dst,
                       const int* __restrict__ lab,
                       int* __restrict__ Li_out,
                       int* __restrict__ count)
{
    int i = blockIdx.x * blockDim.x + threadIdx.x;
    if (i >= NN) return;
    int j = i;
#pragma unroll
    for (int t = 0; t < 8; ++t) j = dst[j];
    int L = lab[j];
    if (!(y_hat[i] > 0.5f)) L = 0;
    Li_out[i] = L;
    if (L > 0) atomicAdd(&count[L], 1);
}

// ---- kernel 8: size-threshold broadcast (in-place int -> float in d_out) ----
__global__ void k_final(const int* __restrict__ Li,
                        const int* __restrict__ count,
                        float* __restrict__ out)
{
    int i = blockIdx.x * blockDim.x + threadIdx.x;
    if (i >= NN) return;
    int L = Li[i];
    float v = (L > 0 && count[L] > 256) ? (float)L : 0.0f;
    out[i] = v;
}

extern "C" void kernel_launch(void* const* d_in, const int* in_sizes, int n_in,
                              void* d_out, int out_size, void* d_ws, size_t ws_size,
                              hipStream_t stream)
{
    const float* y_hat = (const float*)d_in[0];
    const float* df    = (const float*)d_in[1];

    int* W0 = (int*)d_ws;        // dst_ids                (N)
    int* W1 = W0 + NN;           // y1 / mask0 / lab ping  (N)
    int* W2 = W1 + NN;           // y2 / count             (N+1, padded)
    int* W3 = W2 + (NN + 64);    // hs / lab pong (final)  (N)
    float* out = (float*)d_out;

    hipMemsetAsync(W1, 0, (size_t)NN * sizeof(int), stream);           // y1 = 0
    hipMemsetAsync(W2, 0, (size_t)(NN + 1) * sizeof(int), stream);     // y2 = 0

    dim3 blk(256), grd((NN + 255) / 256);
    k_prep<<<grd, blk, 0, stream>>>(y_hat, df, W0, W1);
    k_scatter2<<<grd, blk, 0, stream>>>(W1, W0, W2);
    k_hsum<<<grd, blk, 0, stream>>>(W2, W3);
    k_vthr<<<grd, blk, 0, stream>>>(W3, W1);
    k_erode<<<grd, blk, 0, stream>>>(W1, W3);

    // 300 dilation steps = 30 launches x 10 in-LDS steps, ping-pong W3<->W1
    dim3 gd(WW / BX, HH / BY);   // (16,16)
    int* pa = W3;
    int* pb = W1;
    for (int t = 0; t < 30; ++t) {
        k_dilate<<<gd, 512, 0, stream>>>(pa, pb);
        int* tmp = pa; pa = pb; pb = tmp;
    }
    // 30 swaps (even) -> final labels in W3 (== pa)

    hipMemsetAsync(W2, 0, (size_t)(NN + 1) * sizeof(int), stream);     // count = 0
    k_hist<<<grd, blk, 0, stream>>>(y_hat, W0, pa, (int*)d_out, W2);
    k_final<<<grd, blk, 0, stream>>>((const int*)d_out, W2, out);
}

// Round 17
// 868.255 us; speedup vs baseline: 1.7360x; 1.0724x over previous
//
#include <hip/hip_runtime.h>
#include <stdint.h>

#define HH 1024
#define WW 1536
#define NN (HH * WW)

// ---- dilation tiling ----
#define SS 10                 // steps per launch (halo width)
#define BX 96                 // core tile X (W/BX = 16)
#define BY 32                 // core tile Y (H/BY = 32) -> 512 blocks = 2/CU
#define TX (BX + 2 * SS)      // 116 (halo'd tile X)
#define TY (BY + 2 * SS)      // 52  (halo'd tile Y)
#define LSTRIDE 128           // LDS row stride (ints) = 32 int4 groups exactly
#define LROWS (TY + 2)        // 54 (zero ring top/bottom)
#define NSET (TY / 2)         // 26 wave-sets: each wave covers 2 rows x 32 groups
#define NK 4                  // ceil(NSET / 8 waves)
#define BUF (LROWS * LSTRIDE) // ints per ping-pong buffer (6912 = 27 KB)

static __device__ __forceinline__ int imax(int a, int b) { return a > b ? a : b; }

// ---- kernel 1: dst ids (exact IEEE, no contraction) + fore scatter into y1 ----
__global__ void k_prep(const float* __restrict__ y_hat,
                       const float* __restrict__ df,
                       int* __restrict__ dst_ids,
                       int* __restrict__ y1)
{
    int i = blockIdx.x * blockDim.x + threadIdx.x;
    if (i >= NN) return;
    int r = i / WW, c = i % WW;
    float a = df[i];          // df_hat[0,:,:]
    float b = df[NN + i];     // df_hat[1,:,:]
    float ss  = __fadd_rn(__fmul_rn(a, a), __fmul_rn(b, b));
    float len = __fsqrt_rn(ss);
    float x   = __fadd_rn(len, 1e-19f);
    float ur  = __fdiv_rn(a, x);
    float uc  = __fdiv_rn(b, x);
    float dfc = fminf(fmaxf(len, 3.0f), 6.0f);
    float dr  = __fadd_rn((float)r, __fmul_rn(ur, dfc));
    float dc  = __fadd_rn((float)c, __fmul_rn(uc, dfc));
    dr = fminf(fmaxf(dr, 0.0f), (float)(HH - 1));
    dc = fminf(fmaxf(dc, 0.0f), (float)(WW - 1));
    int ir = (int)rintf(dr);   // round half-to-even, matches jnp/np.round
    int ic = (int)rintf(dc);
    int d = ir * WW + ic;
    dst_ids[i] = d;
    if (y_hat[i] > 0.5f) atomicAdd(&y1[d], 1);
}

// ---- kernel 2: second scatter (y2[dst[i]] += y1[i]) ----
__global__ void k_scatter2(const int* __restrict__ y1,
                           const int* __restrict__ dst,
                           int* __restrict__ y2)
{
    int i = blockIdx.x * blockDim.x + threadIdx.x;
    if (i >= NN) return;
    int v = y1[i];
    if (v) atomicAdd(&y2[dst[i]], v);
}

// ---- kernel 3: horizontal 5-sum of y2 ----
__global__ void k_hsum(const int* __restrict__ y2, int* __restrict__ hs)
{
    int i = blockIdx.x * blockDim.x + threadIdx.x;
    if (i >= NN) return;
    int c = i % WW;
    int s = 0;
#pragma unroll
    for (int d = -2; d <= 2; ++d) {
        int cc = c + d;
        if (cc >= 0 && cc < WW) s += y2[i + d];
    }
    hs[i] = s;
}

// ---- kernel 4: vertical 5-sum + avgpool>=0.5 threshold (exact integer test) ----
__global__ void k_vthr(const int* __restrict__ hs, int* __restrict__ m0)
{
    int i = blockIdx.x * blockDim.x + threadIdx.x;
    if (i >= NN) return;
    int r = i / WW, c = i % WW;
    int s = 0;
#pragma unroll
    for (int d = -2; d <= 2; ++d) {
        int rr = r + d;
        if (rr >= 0 && rr < HH) s += hs[i + d * WW];
    }
    int rows = min(r + 2, HH - 1) - max(r - 2, 0) + 1;
    int cols = min(c + 2, WW - 1) - max(c - 2, 0) + 1;
    m0[i] = (2 * s >= rows * cols) ? 1 : 0;  // s/c >= 0.5 exactly
}

// ---- kernel 5: 3x3-cross erosion (border = foreground) + label init ----
__global__ void k_erode(const int* __restrict__ m0, int* __restrict__ lab)
{
    int i = blockIdx.x * blockDim.x + threadIdx.x;
    if (i >= NN) return;
    int r = i / WW, c = i % WW;
    int m = m0[i];
    if (m) {
        if (r > 0)      m &= m0[i - WW];
        if (r < HH - 1) m &= m0[i + WW];
        if (c > 0)      m &= m0[i - 1];
        if (c < WW - 1) m &= m0[i + 1];
    }
    lab[i] = m ? (i + 1) : 0;
}

// ---- kernel 6: 10 masked 3x3 max-dilation steps, ping-pong LDS ----
// Round-15 wave-aligned layout (all-b128 + width-32 shuffles, conflict-free)
// plus two changes targeting the barrier/latency bound:
//   (a) BY 64->32: 512 blocks -> 2 blocks/CU, so one block's barrier wait
//       overlaps the other's compute (occupancy 2x).
//   (b) in-LDS ping-pong (read buf[cur], write buf[cur^1]) -> ONE
//       __syncthreads per step instead of two (no in-place WAR hazard).
// Invariants unchanged: pads (groups 0,30,31) and ring rows stay zero in both
// buffers (writes there are mid==0-masked to 0); halo staleness one-sided;
// core exact after 10 steps. 2*27 KB = 54 KB LDS/block, 108 KB/CU.
__global__ __launch_bounds__(512) void k_dilate(const int* __restrict__ in,
                                                int* __restrict__ out)
{
    __shared__ int L[2 * BUF];
    const int tx   = threadIdx.x;
    const int wid  = tx >> 6;
    const int lane = tx & 63;
    const int half = lane >> 5;     // which of the wave's 2 rows
    const int g    = lane & 31;     // int4-group within row
    const int r0 = blockIdx.y * BY - SS;
    const int c0 = blockIdx.x * BX - SS;

    // zero both buffers (ring rows, pad cols = reduce_window pad value 0)
    for (int p = tx; p < 2 * BUF; p += 512) L[p] = 0;
    __syncthreads();
    // load halo'd tile into buffer 0
    for (int p = tx; p < TY * TX; p += 512) {
        int tr = p / TX, tc = p - tr * TX;
        int gr = r0 + tr, gc = c0 + tc;
        int v = 0;
        if (gr >= 0 && gr < HH && gc >= 0 && gc < WW) v = in[gr * WW + gc];
        L[(tr + 1) * LSTRIDE + 4 + tc] = v;
    }
    __syncthreads();

    int cur = 0;
    for (int s = 0; s < SS; ++s) {
        const int rbase = cur * BUF;
        const int wbase = (cur ^ 1) * BUF;
#pragma unroll
        for (int k = 0; k < NK; ++k) {
            int S = wid + 8 * k;            // wave-uniform set index
            if (S < NSET) {                 // wave-uniform branch
                int rr  = 1 + 2 * S + half; // rows 1..52
                int idx = rbase + rr * LSTRIDE + 4 * g;
                int4 mid = *(const int4*)&L[idx];
                int4 up  = *(const int4*)&L[idx - LSTRIDE];
                int4 dn  = *(const int4*)&L[idx + LSTRIDE];
                int ul = __shfl_up(up.w, 1, 32);
                int ml = __shfl_up(mid.w, 1, 32);
                int dl = __shfl_up(dn.w, 1, 32);
                int uR = __shfl_down(up.x, 1, 32);
                int mR = __shfl_down(mid.x, 1, 32);
                int dR = __shfl_down(dn.x, 1, 32);
                int vl = imax(imax(ul, ml), dl);
                int v0 = imax(imax(up.x, mid.x), dn.x);
                int v1 = imax(imax(up.y, mid.y), dn.y);
                int v2 = imax(imax(up.z, mid.z), dn.z);
                int v3 = imax(imax(up.w, mid.w), dn.w);
                int vr = imax(imax(uR, mR), dR);
                int4 res;
                res.x = (mid.x > 0) ? imax(imax(vl, v0), v1) : 0;
                res.y = (mid.y > 0) ? imax(imax(v0, v1), v2) : 0;
                res.z = (mid.z > 0) ? imax(imax(v1, v2), v3) : 0;
                res.w = (mid.w > 0) ? imax(imax(v2, v3), vr) : 0;
                *(int4*)&L[wbase + rr * LSTRIDE + 4 * g] = res;
            }
        }
        __syncthreads();
        cur ^= 1;
    }

    // store exact core (SS even -> final state back in buffer `cur`)
    const int fbase = cur * BUF;
    for (int q = tx; q < BX * BY; q += 512) {
        int cr = q / BX, cc = q - cr * BX;
        out[(blockIdx.y * BY + cr) * WW + blockIdx.x * BX + cc] =
            L[fbase + (SS + cr + 1) * LSTRIDE + 4 + SS + cc];
    }
}

// ---- kernel 7: 8-deep gather chain + fore mask + size histogram ----
__global__ void k_hist(const float* __restrict__ y_hat,
                       const int* __restrict__ dst,
                       const int* __restrict__ lab,
                       int* __restrict__ Li_out,
                       int* __restrict__ count)
{
    int i = blockIdx.x * blockDim.x + threadIdx.x;
    if (i >= NN) return;
    int j = i;
#pragma unroll
    for (int t = 0; t < 8; ++t) j = dst[j];
    int L = lab[j];
    if (!(y_hat[i] > 0.5f)) L = 0;
    Li_out[i] = L;
    if (L > 0) atomicAdd(&count[L], 1);
}

// ---- kernel 8: size-threshold broadcast (in-place int -> float in d_out) ----
__global__ void k_final(const int* __restrict__ Li,
                        const int* __restrict__ count,
                        float* __restrict__ out)
{
    int i = blockIdx.x * blockDim.x + threadIdx.x;
    if (i >= NN) return;
    int L = Li[i];
    float v = (L > 0 && count[L] > 256) ? (float)L : 0.0f;
    out[i] = v;
}

extern "C" void kernel_launch(void* const* d_in, const int* in_sizes, int n_in,
                              void* d_out, int out_size, void* d_ws, size_t ws_size,
                              hipStream_t stream)
{
    const float* y_hat = (const float*)d_in[0];
    const float* df    = (const float*)d_in[1];

    int* W0 = (int*)d_ws;        // dst_ids                (N)
    int* W1 = W0 + NN;           // y1 / mask0 / lab ping  (N)
    int* W2 = W1 + NN;           // y2 / count             (N+1, padded)
    int* W3 = W2 + (NN + 64);    // hs / lab pong (final)  (N)
    float* out = (float*)d_out;

    hipMemsetAsync(W1, 0, (size_t)NN * sizeof(int), stream);           // y1 = 0
    hipMemsetAsync(W2, 0, (size_t)(NN + 1) * sizeof(int), stream);     // y2 = 0

    dim3 blk(256), grd((NN + 255) / 256);
    k_prep<<<grd, blk, 0, stream>>>(y_hat, df, W0, W1);
    k_scatter2<<<grd, blk, 0, stream>>>(W1, W0, W2);
    k_hsum<<<grd, blk, 0, stream>>>(W2, W3);
    k_vthr<<<grd, blk, 0, stream>>>(W3, W1);
    k_erode<<<grd, blk, 0, stream>>>(W1, W3);

    // 300 dilation steps = 30 launches x 10 in-LDS steps, ping-pong W3<->W1
    dim3 gd(WW / BX, HH / BY);   // (16,32) = 512 blocks = 2 per CU
    int* pa = W3;
    int* pb = W1;
    for (int t = 0; t < 30; ++t) {
        k_dilate<<<gd, 512, 0, stream>>>(pa, pb);
        int* tmp = pa; pa = pb; pb = tmp;
    }
    // 30 swaps (even) -> final labels in W3 (== pa)

    hipMemsetAsync(W2, 0, (size_t)(NN + 1) * sizeof(int), stream);     // count = 0
    k_hist<<<grd, blk, 0, stream>>>(y_hat, W0, pa, (int*)d_out, W2);
    k_final<<<grd, blk, 0, stream>>>((const int*)d_out, W2, out);
}

// Round 18
// 692.181 us; speedup vs baseline: 2.1776x; 1.2544x over previous
//
#include <hip/hip_runtime.h>
#include <stdint.h>

#define HH 1024
#define WW 1536
#define NN (HH * WW)

// ---- dilation tiling ----
#define SS 10                 // steps per launch (halo width)
#define BX 96                 // core tile X (W/BX = 16)
#define BY 32                 // core tile Y (H/BY = 32) -> 512 blocks = 2/CU
#define TX (BX + 2 * SS)      // 116 (halo'd tile X)
#define TY (BY + 2 * SS)      // 52  (halo'd tile Y)
#define LSTRIDE 128           // LDS row stride (ints) = 32 int4 groups exactly
#define LROWS (TY + 2)        // 54 (zero ring top/bottom)
#define NSET (TY / 2)         // 26 wave-sets: each wave covers 2 rows x 32 groups
#define NK 4                  // ceil(NSET / 8 waves)
#define BUF (LROWS * LSTRIDE) // ints per ping-pong buffer (6912 = 27 KB)

static __device__ __forceinline__ int imax(int a, int b) { return a > b ? a : b; }
static __device__ __forceinline__ int imax3(int a, int b, int c) {
    return imax(imax(a, b), c);
}

// ---- kernel 1: dst ids (exact IEEE, no contraction) + fore scatter into y1 ----
__global__ void k_prep(const float* __restrict__ y_hat,
                       const float* __restrict__ df,
                       int* __restrict__ dst_ids,
                       int* __restrict__ y1)
{
    int i = blockIdx.x * blockDim.x + threadIdx.x;
    if (i >= NN) return;
    int r = i / WW, c = i % WW;
    float a = df[i];          // df_hat[0,:,:]
    float b = df[NN + i];     // df_hat[1,:,:]
    float ss  = __fadd_rn(__fmul_rn(a, a), __fmul_rn(b, b));
    float len = __fsqrt_rn(ss);
    float x   = __fadd_rn(len, 1e-19f);
    float ur  = __fdiv_rn(a, x);
    float uc  = __fdiv_rn(b, x);
    float dfc = fminf(fmaxf(len, 3.0f), 6.0f);
    float dr  = __fadd_rn((float)r, __fmul_rn(ur, dfc));
    float dc  = __fadd_rn((float)c, __fmul_rn(uc, dfc));
    dr = fminf(fmaxf(dr, 0.0f), (float)(HH - 1));
    dc = fminf(fmaxf(dc, 0.0f), (float)(WW - 1));
    int ir = (int)rintf(dr);   // round half-to-even, matches jnp/np.round
    int ic = (int)rintf(dc);
    int d = ir * WW + ic;
    dst_ids[i] = d;
    if (y_hat[i] > 0.5f) atomicAdd(&y1[d], 1);
}

// ---- kernel 2: second scatter (y2[dst[i]] += y1[i]) ----
__global__ void k_scatter2(const int* __restrict__ y1,
                           const int* __restrict__ dst,
                           int* __restrict__ y2)
{
    int i = blockIdx.x * blockDim.x + threadIdx.x;
    if (i >= NN) return;
    int v = y1[i];
    if (v) atomicAdd(&y2[dst[i]], v);
}

// ---- kernel 3: horizontal 5-sum of y2 ----
__global__ void k_hsum(const int* __restrict__ y2, int* __restrict__ hs)
{
    int i = blockIdx.x * blockDim.x + threadIdx.x;
    if (i >= NN) return;
    int c = i % WW;
    int s = 0;
#pragma unroll
    for (int d = -2; d <= 2; ++d) {
        int cc = c + d;
        if (cc >= 0 && cc < WW) s += y2[i + d];
    }
    hs[i] = s;
}

// ---- kernel 4: vertical 5-sum + avgpool>=0.5 threshold (exact integer test) ----
__global__ void k_vthr(const int* __restrict__ hs, int* __restrict__ m0)
{
    int i = blockIdx.x * blockDim.x + threadIdx.x;
    if (i >= NN) return;
    int r = i / WW, c = i % WW;
    int s = 0;
#pragma unroll
    for (int d = -2; d <= 2; ++d) {
        int rr = r + d;
        if (rr >= 0 && rr < HH) s += hs[i + d * WW];
    }
    int rows = min(r + 2, HH - 1) - max(r - 2, 0) + 1;
    int cols = min(c + 2, WW - 1) - max(c - 2, 0) + 1;
    m0[i] = (2 * s >= rows * cols) ? 1 : 0;  // s/c >= 0.5 exactly
}

// ---- kernel 5: 3x3-cross erosion (border = foreground) + label init ----
__global__ void k_erode(const int* __restrict__ m0, int* __restrict__ lab)
{
    int i = blockIdx.x * blockDim.x + threadIdx.x;
    if (i >= NN) return;
    int r = i / WW, c = i % WW;
    int m = m0[i];
    if (m) {
        if (r > 0)      m &= m0[i - WW];
        if (r < HH - 1) m &= m0[i + WW];
        if (c > 0)      m &= m0[i - 1];
        if (c < WW - 1) m &= m0[i + 1];
    }
    lab[i] = m ? (i + 1) : 0;
}

// ---- kernel 6: 10 masked 3x3 max-dilation steps, ping-pong LDS ----
// DS-throughput-optimized (Round-17 diagnosis: LDS-issue bound, 84 cyc/set):
//   (a) vertical-max-first: vm = max3(up,mid,dn) in VALU, then only TWO
//       shuffles (vm.w up, vm.x down) instead of six.
//   (b) mid-in-register: with ping-pong, next step's mid IS the res this wave
//       just wrote -> keep m[k] in VGPRs, skip the mid ds_read.
// Per set per step: 2 ds_read_b128 + 2 shuffles + 1 ds_write_b128 (~48 cyc,
// was ~84). Algebra identical: res.x = mid.x>0 ? max(vl,vm.x,vm.y) : 0, etc.
// Invariants unchanged: pad groups (0,30,31) and ring rows are zero in both
// buffers and in m[] (mid==0 masks every write there to 0); halo staleness
// one-sided; core exact after 10 steps. 2*27 KB = 54 KB LDS, 2 blocks/CU.
__global__ __launch_bounds__(512) void k_dilate(const int* __restrict__ in,
                                                int* __restrict__ out)
{
    __shared__ int L[2 * BUF];
    const int tx   = threadIdx.x;
    const int wid  = tx >> 6;
    const int lane = tx & 63;
    const int half = lane >> 5;     // which of the wave's 2 rows
    const int g    = lane & 31;     // int4-group within row
    const int r0 = blockIdx.y * BY - SS;
    const int c0 = blockIdx.x * BX - SS;

    // zero both buffers (ring rows, pad cols = reduce_window pad value 0)
    for (int p = tx; p < 2 * BUF; p += 512) L[p] = 0;
    __syncthreads();
    // load halo'd tile into buffer 0
    for (int p = tx; p < TY * TX; p += 512) {
        int tr = p / TX, tc = p - tr * TX;
        int gr = r0 + tr, gc = c0 + tc;
        int v = 0;
        if (gr >= 0 && gr < HH && gc >= 0 && gc < WW) v = in[gr * WW + gc];
        L[(tr + 1) * LSTRIDE + 4 + tc] = v;
    }
    __syncthreads();

    // prime the per-wave mid registers from buffer 0
    int4 m[NK];
#pragma unroll
    for (int k = 0; k < NK; ++k) {
        int S = wid + 8 * k;
        m[k] = make_int4(0, 0, 0, 0);
        if (S < NSET) {
            int rr = 1 + 2 * S + half;
            m[k] = *(const int4*)&L[rr * LSTRIDE + 4 * g];
        }
    }

    int cur = 0;
    for (int s = 0; s < SS; ++s) {
        const int rbase = cur * BUF;
        const int wbase = (cur ^ 1) * BUF;
#pragma unroll
        for (int k = 0; k < NK; ++k) {
            int S = wid + 8 * k;            // wave-uniform set index
            if (S < NSET) {                 // wave-uniform branch
                int rr  = 1 + 2 * S + half; // rows 1..52
                int idx = rbase + rr * LSTRIDE + 4 * g;
                int4 mid = m[k];
                int4 up  = *(const int4*)&L[idx - LSTRIDE];
                int4 dn  = *(const int4*)&L[idx + LSTRIDE];
                int4 vm;
                vm.x = imax3(up.x, mid.x, dn.x);
                vm.y = imax3(up.y, mid.y, dn.y);
                vm.z = imax3(up.z, mid.z, dn.z);
                vm.w = imax3(up.w, mid.w, dn.w);
                int vl = __shfl_up(vm.w, 1, 32);
                int vr = __shfl_down(vm.x, 1, 32);
                int4 res;
                res.x = (mid.x > 0) ? imax3(vl, vm.x, vm.y) : 0;
                res.y = (mid.y > 0) ? imax3(vm.x, vm.y, vm.z) : 0;
                res.z = (mid.z > 0) ? imax3(vm.y, vm.z, vm.w) : 0;
                res.w = (mid.w > 0) ? imax3(vm.z, vm.w, vr) : 0;
                *(int4*)&L[wbase + rr * LSTRIDE + 4 * g] = res;
                m[k] = res;
            }
        }
        __syncthreads();
        cur ^= 1;
    }

    // store exact core (SS even -> final state back in buffer `cur`)
    const int fbase = cur * BUF;
    for (int q = tx; q < BX * BY; q += 512) {
        int cr = q / BX, cc = q - cr * BX;
        out[(blockIdx.y * BY + cr) * WW + blockIdx.x * BX + cc] =
            L[fbase + (SS + cr + 1) * LSTRIDE + 4 + SS + cc];
    }
}

// ---- kernel 7: 8-deep gather chain + fore mask + size histogram ----
__global__ void k_hist(const float* __restrict__ y_hat,
                       const int* __restrict__ dst,
                       const int* __restrict__ lab,
                       int* __restrict__ Li_out,
                       int* __restrict__ count)
{
    int i = blockIdx.x * blockDim.x + threadIdx.x;
    if (i >= NN) return;
    int j = i;
#pragma unroll
    for (int t = 0; t < 8; ++t) j = dst[j];
    int L = lab[j];
    if (!(y_hat[i] > 0.5f)) L = 0;
    Li_out[i] = L;
    if (L > 0) atomicAdd(&count[L], 1);
}

// ---- kernel 8: size-threshold broadcast (in-place int -> float in d_out) ----
__global__ void k_final(const int* __restrict__ Li,
                        const int* __restrict__ count,
                        float* __restrict__ out)
{
    int i = blockIdx.x * blockDim.x + threadIdx.x;
    if (i >= NN) return;
    int L = Li[i];
    float v = (L > 0 && count[L] > 256) ? (float)L : 0.0f;
    out[i] = v;
}

extern "C" void kernel_launch(void* const* d_in, const int* in_sizes, int n_in,
                              void* d_out, int out_size, void* d_ws, size_t ws_size,
                              hipStream_t stream)
{
    const float* y_hat = (const float*)d_in[0];
    const float* df    = (const float*)d_in[1];

    int* W0 = (int*)d_ws;        // dst_ids                (N)
    int* W1 = W0 + NN;           // y1 / mask0 / lab ping  (N)
    int* W2 = W1 + NN;           // y2 / count             (N+1, padded)
    int* W3 = W2 + (NN + 64);    // hs / lab pong (final)  (N)
    float* out = (float*)d_out;

    hipMemsetAsync(W1, 0, (size_t)NN * sizeof(int), stream);           // y1 = 0
    hipMemsetAsync(W2, 0, (size_t)(NN + 1) * sizeof(int), stream);     // y2 = 0

    dim3 blk(256), grd((NN + 255) / 256);
    k_prep<<<grd, blk, 0, stream>>>(y_hat, df, W0, W1);
    k_scatter2<<<grd, blk, 0, stream>>>(W1, W0, W2);
    k_hsum<<<grd, blk, 0, stream>>>(W2, W3);
    k_vthr<<<grd, blk, 0, stream>>>(W3, W1);
    k_erode<<<grd, blk, 0, stream>>>(W1, W3);

    // 300 dilation steps = 30 launches x 10 in-LDS steps, ping-pong W3<->W1
    dim3 gd(WW / BX, HH / BY);   // (16,32) = 512 blocks = 2 per CU
    int* pa = W3;
    int* pb = W1;
    for (int t = 0; t < 30; ++t) {
        k_dilate<<<gd, 512, 0, stream>>>(pa, pb);
        int* tmp = pa; pa = pb; pb = tmp;
    }
    // 30 swaps (even) -> final labels in W3 (== pa)

    hipMemsetAsync(W2, 0, (size_t)(NN + 1) * sizeof(int), stream);     // count = 0
    k_hist<<<grd, blk, 0, stream>>>(y_hat, W0, pa, (int*)d_out, W2);
    k_final<<<grd, blk, 0, stream>>>((const int*)d_out, W2, out);
}